// Round 1
// baseline (1042.854 us; speedup 1.0000x reference)
//
#include <hip/hip_runtime.h>
#include <hip/hip_bf16.h>
#include <math.h>

typedef __bf16 bf16x8 __attribute__((ext_vector_type(8)));
typedef __bf16 bf16x4 __attribute__((ext_vector_type(4)));
typedef float  f32x4  __attribute__((ext_vector_type(4)));

#define SRC 4096
#define BSZ 64
#define EMB 512
#define LDA 520   // padded bf16 LDS row stride: 1040B -> bank offset 4/row, 2-way (free)

__device__ __forceinline__ float fast_tanh(float x) {
  float ax = fabsf(x);
  float t  = __expf(-2.0f * ax);
  float r  = 1.0f - 2.0f * t / (1.0f + t);
  return copysignf(r, x);
}

// ---- normed_v = g * v / ||v|| ----
__global__ void prep_nv(const float* __restrict__ v, const float* __restrict__ g,
                        float* __restrict__ nv) {
  __shared__ float red[256];
  int t = threadIdx.x;
  float a = v[t], b = v[t + 256];
  red[t] = a * a + b * b;
  __syncthreads();
  for (int o = 128; o > 0; o >>= 1) {
    if (t < o) red[t] += red[t + o];
    __syncthreads();
  }
  float scale = g[0] / sqrtf(red[0]);
  nv[t]       = a * scale;
  nv[t + 256] = b * scale;
}

// ---- pqb[b][e] = sum_q query[b][q] * Wq[e][q] + bias[e] ----
__global__ void prep_pqb(const float* __restrict__ query, const float* __restrict__ Wq,
                         const float* __restrict__ bias, float* __restrict__ pqb) {
  __shared__ float q[EMB];
  int b = blockIdx.x, t = threadIdx.x;
  q[t]       = query[b * EMB + t];
  q[t + 256] = query[b * EMB + t + 256];
  __syncthreads();
  for (int e = t; e < EMB; e += 256) {
    const float* wr = Wq + (size_t)e * EMB;
    float acc = 0.f;
#pragma unroll 4
    for (int k = 0; k < EMB; k += 4) {
      float4 qv = *reinterpret_cast<const float4*>(&q[k]);
      float4 wv = *reinterpret_cast<const float4*>(&wr[k]);
      acc += qv.x * wv.x + qv.y * wv.y + qv.z * wv.z + qv.w * wv.w;
    }
    pqb[b * EMB + e] = acc + bias[e];
  }
}

// ---- pack Wv (f32 [e][v]) into bf16 b-fragment order:
//      wvpk[((nsub*16 + ks)*64 + lane)*8 + j] = Wv[nsub*16 + (lane&15)][ks*32 + (lane>>4)*8 + j]
__global__ void pack_wv(const float* __restrict__ Wv, __bf16* __restrict__ wvpk) {
  int tid  = blockIdx.x * 256 + threadIdx.x;  // 0..32767
  int lane = tid & 63;
  int ks   = (tid >> 6) & 15;
  int nsub = tid >> 10;
  int e  = nsub * 16 + (lane & 15);
  int k0 = ks * 32 + (lane >> 4) * 8;
  const float* src = Wv + (size_t)e * EMB + k0;
  bf16x8 o;
#pragma unroll
  for (int j = 0; j < 8; ++j) o[j] = (__bf16)src[j];
  *reinterpret_cast<bf16x8*>(wvpk + (size_t)tid * 8) = o;
}

// ---- fused scores: scoresT[b][s] = sum_e nv[e] * tanh(key[s][b][e] + pqb[b][e]) ----
// one block per s; A = value[s] (64x512) bf16-resident in LDS; B frags streamed from L2.
__global__ __launch_bounds__(256, 2)
void scores_kernel(const float* __restrict__ value, const float* __restrict__ pqb,
                   const float* __restrict__ nv, const __bf16* __restrict__ wvpk,
                   float* __restrict__ scoresT) {
  __shared__ __bf16 As[BSZ * LDA];
  __shared__ float red[4][BSZ];
  const int s = blockIdx.x;
  const int t = threadIdx.x;

  // stage value[s] (128 KB f32, coalesced float4) -> bf16 LDS
  const float* src = value + (size_t)s * (BSZ * EMB);
#pragma unroll
  for (int i = 0; i < 32; ++i) {
    int e0 = (i * 256 + t) * 4;
    float4 vv = *reinterpret_cast<const float4*>(src + e0);
    int row = e0 >> 9;
    int col = e0 & 511;
    bf16x4 o;
    o[0] = (__bf16)vv.x; o[1] = (__bf16)vv.y; o[2] = (__bf16)vv.z; o[3] = (__bf16)vv.w;
    *reinterpret_cast<bf16x4*>(&As[row * LDA + col]) = o;
  }
  __syncthreads();

  const int w  = t >> 6;   // wave id: owns n in [outer*256 + w*64, +64)
  const int l  = t & 63;
  const int lr = l & 15;   // row/col within 16
  const int lk = l >> 4;   // k-group / row-quad

  float sc[16];
#pragma unroll
  for (int i = 0; i < 16; ++i) sc[i] = 0.f;

  for (int outer = 0; outer < 2; ++outer) {
    const int nbase = outer * 256 + w * 64;
    f32x4 acc[4][4];
#pragma unroll
    for (int m = 0; m < 4; ++m)
#pragma unroll
      for (int n = 0; n < 4; ++n)
#pragma unroll
        for (int r = 0; r < 4; ++r) acc[m][n][r] = 0.f;

#pragma unroll 2
    for (int ks = 0; ks < 16; ++ks) {
      bf16x8 a[4], bfr[4];
#pragma unroll
      for (int m = 0; m < 4; ++m)
        a[m] = *reinterpret_cast<const bf16x8*>(&As[(m * 16 + lr) * LDA + ks * 32 + lk * 8]);
#pragma unroll
      for (int n = 0; n < 4; ++n)
        bfr[n] = *reinterpret_cast<const bf16x8*>(
            wvpk + ((size_t)((((nbase >> 4) + n) * 16 + ks) * 64 + l)) * 8);
#pragma unroll
      for (int m = 0; m < 4; ++m)
#pragma unroll
        for (int n = 0; n < 4; ++n)
          acc[m][n] = __builtin_amdgcn_mfma_f32_16x16x32_bf16(a[m], bfr[n], acc[m][n], 0, 0, 0);
    }

    // fused epilogue: sc[row] += nv[e] * tanh(C + pqb[b][e])
#pragma unroll
    for (int n = 0; n < 4; ++n) {
      int col = nbase + n * 16 + lr;
      float nvc = nv[col];
#pragma unroll
      for (int m = 0; m < 4; ++m) {
#pragma unroll
        for (int r = 0; r < 4; ++r) {
          int brow = m * 16 + lk * 4 + r;  // batch index b (block covers one s)
          float x = acc[m][n][r] + pqb[brow * EMB + col];
          sc[m * 4 + r] += nvc * fast_tanh(x);
        }
      }
    }
  }

  // reduce the 16 lanes sharing (lk, reg), then combine 4 waves via LDS
#pragma unroll
  for (int i = 0; i < 16; ++i) {
    float vsum = sc[i];
#pragma unroll
    for (int off = 1; off < 16; off <<= 1) vsum += __shfl_xor(vsum, off, 64);
    if (lr == 0) red[w][(i >> 2) * 16 + lk * 4 + (i & 3)] = vsum;
  }
  __syncthreads();
  if (t < BSZ) {
    float total = red[0][t] + red[1][t] + red[2][t] + red[3][t];
    scoresT[(size_t)t * SRC + s] = total;
  }
}

// ---- softmax over s for each b; writes pT[b][s] and both attn outputs [s][b] ----
__global__ void softmax_k(const float* __restrict__ scoresT, const unsigned char* __restrict__ mask,
                          float* __restrict__ pT, float* __restrict__ attn0,
                          float* __restrict__ attn1) {
  __shared__ float buf[SRC];
  __shared__ float red[256];
  int b = blockIdx.x, t = threadIdx.x;
  float mx = -1e30f;
  for (int s = t; s < SRC; s += 256) {
    float x = scoresT[(size_t)b * SRC + s];
    if (mask[(size_t)s * BSZ + b]) x = -1e30f;
    buf[s] = x;
    mx = fmaxf(mx, x);
  }
  red[t] = mx; __syncthreads();
  for (int o = 128; o > 0; o >>= 1) { if (t < o) red[t] = fmaxf(red[t], red[t + o]); __syncthreads(); }
  mx = red[0]; __syncthreads();
  float sum = 0.f;
  for (int s = t; s < SRC; s += 256) { float e = __expf(buf[s] - mx); buf[s] = e; sum += e; }
  red[t] = sum; __syncthreads();
  for (int o = 128; o > 0; o >>= 1) { if (t < o) red[t] += red[t + o]; __syncthreads(); }
  float inv = 1.0f / red[0];
  for (int s = t; s < SRC; s += 256) {
    float p = buf[s] * inv;
    pT[(size_t)b * SRC + s] = p;
    attn0[(size_t)s * BSZ + b] = p;
    attn1[(size_t)s * BSZ + b] = p;
  }
}

// ---- context partials: parts[c][b][v] = sum_{s in chunk c} p[s][b]*value[s][b][v] ----
__global__ void ctx_partial(const float* __restrict__ value, const float* __restrict__ pT,
                            float* __restrict__ parts) {
  int blk = blockIdx.x;      // c*64 + b
  int c = blk >> 6;
  int b = blk & 63;
  int t = threadIdx.x;
  float2 acc = make_float2(0.f, 0.f);
#pragma unroll 4
  for (int i = 0; i < 128; ++i) {
    int s = c * 128 + i;
    float p = pT[(size_t)b * SRC + s];
    float2 vv = *reinterpret_cast<const float2*>(value + ((size_t)(s * BSZ + b)) * EMB + t * 2);
    acc.x += p * vv.x;
    acc.y += p * vv.y;
  }
  *reinterpret_cast<float2*>(parts + (size_t)blk * EMB + t * 2) = acc;
}

__global__ void ctx_reduce(const float* __restrict__ parts, float* __restrict__ out_ctx) {
  int idx = blockIdx.x * 256 + threadIdx.x;  // b*512 + v
  float acc = 0.f;
#pragma unroll
  for (int c = 0; c < 32; ++c) acc += parts[(size_t)c * (BSZ * EMB) + idx];
  out_ctx[idx] = acc;
}

extern "C" void kernel_launch(void* const* d_in, const int* in_sizes, int n_in,
                              void* d_out, int out_size, void* d_ws, size_t ws_size,
                              hipStream_t stream) {
  const float* query        = (const float*)d_in[0];
  const float* value        = (const float*)d_in[1];
  const unsigned char* mask = (const unsigned char*)d_in[2];
  const float* Wq           = (const float*)d_in[3];
  const float* Wv           = (const float*)d_in[4];
  const float* v            = (const float*)d_in[5];
  const float* bias         = (const float*)d_in[6];
  const float* g            = (const float*)d_in[7];

  float* out_ctx = (float*)d_out;            // [64][512]
  float* attn0   = (float*)d_out + BSZ * EMB;  // [4096][64]
  float* attn1   = attn0 + SRC * BSZ;

  char* ws = (char*)d_ws;
  float*  nv      = (float*)(ws);                              // 2 KB
  float*  pqb     = (float*)(ws + 2048);                       // 128 KB
  __bf16* wvpk    = (__bf16*)(ws + 2048 + 131072);             // 512 KB
  float*  scoresT = (float*)(ws + 2048 + 131072 + 524288);     // 1 MB [b][s]
  float*  pT      = scoresT + SRC * BSZ;                       // 1 MB [b][s]
  float*  parts   = pT + SRC * BSZ;                            // 4 MB [32][64][512]

  prep_nv<<<1, 256, 0, stream>>>(v, g, nv);
  prep_pqb<<<BSZ, 256, 0, stream>>>(query, Wq, bias, pqb);
  pack_wv<<<128, 256, 0, stream>>>(Wv, wvpk);
  scores_kernel<<<SRC, 256, 0, stream>>>(value, pqb, nv, wvpk, scoresT);
  softmax_k<<<BSZ, 256, 0, stream>>>(scoresT, mask, pT, attn0, attn1);
  ctx_partial<<<BSZ * 32, 256, 0, stream>>>(value, pT, parts);
  ctx_reduce<<<128, 256, 0, stream>>>(parts, out_ctx);
}

// Round 2
// 1029.878 us; speedup vs baseline: 1.0126x; 1.0126x over previous
//
#include <hip/hip_runtime.h>
#include <hip/hip_bf16.h>
#include <math.h>

typedef __bf16 bf16x8 __attribute__((ext_vector_type(8)));
typedef __bf16 bf16x4 __attribute__((ext_vector_type(4)));
typedef float  f32x4  __attribute__((ext_vector_type(4)));

#define SRC 4096
#define BSZ 64
#define EMB 512

__device__ __forceinline__ float fast_tanh(float x) {
  float ax = fabsf(x);
  float t  = __expf(-2.0f * ax);
  float r  = 1.0f - 2.0f * t / (1.0f + t);
  return copysignf(r, x);
}

// ---- normed_v = g * v / ||v|| ----
__global__ void prep_nv(const float* __restrict__ v, const float* __restrict__ g,
                        float* __restrict__ nv) {
  __shared__ float red[256];
  int t = threadIdx.x;
  float a = v[t], b = v[t + 256];
  red[t] = a * a + b * b;
  __syncthreads();
  for (int o = 128; o > 0; o >>= 1) {
    if (t < o) red[t] += red[t + o];
    __syncthreads();
  }
  float scale = g[0] / sqrtf(red[0]);
  nv[t]       = a * scale;
  nv[t + 256] = b * scale;
}

// ---- pqb[b][e] = sum_q query[b][q] * Wq[e][q] + bias[e] ----
// 128 blocks: b = blk>>1, e = (blk&1)*256 + t
__global__ void prep_pqb(const float* __restrict__ query, const float* __restrict__ Wq,
                         const float* __restrict__ bias, float* __restrict__ pqb) {
  __shared__ float q[EMB];
  int b = blockIdx.x >> 1, t = threadIdx.x;
  int e = (blockIdx.x & 1) * 256 + t;
  q[t]       = query[b * EMB + t];
  q[t + 256] = query[b * EMB + t + 256];
  __syncthreads();
  const float* wr = Wq + (size_t)e * EMB;
  float a0 = 0.f, a1 = 0.f;
#pragma unroll 8
  for (int k = 0; k < EMB; k += 8) {
    float4 q0 = *reinterpret_cast<const float4*>(&q[k]);
    float4 w0 = *reinterpret_cast<const float4*>(&wr[k]);
    float4 q1 = *reinterpret_cast<const float4*>(&q[k + 4]);
    float4 w1 = *reinterpret_cast<const float4*>(&wr[k + 4]);
    a0 += q0.x * w0.x + q0.y * w0.y + q0.z * w0.z + q0.w * w0.w;
    a1 += q1.x * w1.x + q1.y * w1.y + q1.z * w1.z + q1.w * w1.w;
  }
  pqb[b * EMB + e] = a0 + a1 + bias[e];
}

// ---- pack Wv (f32 [e][v]) into bf16 b-fragment order ----
__global__ void pack_wv(const float* __restrict__ Wv, __bf16* __restrict__ wvpk) {
  int tid  = blockIdx.x * 256 + threadIdx.x;  // 0..32767
  int lane = tid & 63;
  int ks   = (tid >> 6) & 15;
  int nsub = tid >> 10;
  int e  = nsub * 16 + (lane & 15);
  int k0 = ks * 32 + (lane >> 4) * 8;
  const float* src = Wv + (size_t)e * EMB + k0;
  bf16x8 o;
#pragma unroll
  for (int j = 0; j < 8; ++j) o[j] = (__bf16)src[j];
  *reinterpret_cast<bf16x8*>(wvpk + (size_t)tid * 8) = o;
}

// ---- fused scores: scoresT[b][s] = sum_e nv[e] * tanh(key[s][b][e] + pqb[b][e])
// 512 threads, 8 waves; wave w covers cols [w*64, w*64+64); single N-pass.
// K chunked into 4 x 128 cols, double-buffered LDS (xor-swizzled, conflict-free).
__global__ __launch_bounds__(512, 4)
void scores_kernel(const float* __restrict__ value, const float* __restrict__ pqb,
                   const float* __restrict__ nv, const __bf16* __restrict__ wvpk,
                   float* __restrict__ scoresT) {
  __shared__ __bf16 As[2][64 * 128];   // 2 x 16 KB, swizzled: elem(row, col) at row*128 + ((col>>3)^(row&7))*8 + (col&7)
  __shared__ float red[8][BSZ];
  const int s = blockIdx.x;
  const int t = threadIdx.x;
  const int w  = t >> 6;
  const int l  = t & 63;
  const int lr = l & 15;
  const int lk = l >> 4;

  // staging geometry: thread t covers row = t>>3, 4 float4s at cols (t&7)*4 + j*32
  const int srow = t >> 3;
  const int ssub = t & 7;
  const float* sbase = value + (size_t)s * (BSZ * EMB) + (size_t)srow * EMB + ssub * 4;

  float4 h0[4], h1[4];
  auto issue = [&](int c, float4* h) {
    const float* p = sbase + c * 128;
#pragma unroll
    for (int j = 0; j < 4; ++j) h[j] = *reinterpret_cast<const float4*>(p + j * 32);
  };
  auto write_lds = [&](int buf, const float4* h) {
#pragma unroll
    for (int j = 0; j < 4; ++j) {
      int kg  = (ssub >> 1) + j * 4;
      int kgp = kg ^ (srow & 7);
      bf16x4 o;
      o[0] = (__bf16)h[j].x; o[1] = (__bf16)h[j].y;
      o[2] = (__bf16)h[j].z; o[3] = (__bf16)h[j].w;
      *reinterpret_cast<bf16x4*>(&As[buf][srow * 128 + kgp * 8 + (ssub & 1) * 4]) = o;
    }
  };

  f32x4 acc[4][4];
#pragma unroll
  for (int m = 0; m < 4; ++m)
#pragma unroll
    for (int n = 0; n < 4; ++n)
#pragma unroll
      for (int r = 0; r < 4; ++r) acc[m][n][r] = 0.f;

  auto compute_chunk = [&](int buf, int c) {
#pragma unroll
    for (int ks = 0; ks < 4; ++ks) {
      const int ksg = c * 4 + ks;
      bf16x8 bq[4];
#pragma unroll
      for (int n = 0; n < 4; ++n) {
        int nt = w * 4 + n;
        bq[n] = *reinterpret_cast<const bf16x8*>(
            wvpk + ((size_t)((nt * 16 + ksg) * 64 + l)) * 8);
      }
      const int kgp = ((ks * 4 + lk) ^ (lr & 7)) * 8;
#pragma unroll
      for (int m = 0; m < 4; ++m) {
        bf16x8 a = *reinterpret_cast<const bf16x8*>(&As[buf][(m * 16 + lr) * 128 + kgp]);
#pragma unroll
        for (int n = 0; n < 4; ++n)
          acc[m][n] = __builtin_amdgcn_mfma_f32_16x16x32_bf16(a, bq[n], acc[m][n], 0, 0, 0);
      }
    }
  };

  issue(0, h0);
  issue(1, h1);
  write_lds(0, h0);
  write_lds(1, h1);
  __syncthreads();
  issue(2, h0);
  issue(3, h1);
  compute_chunk(0, 0);
  compute_chunk(1, 1);
  __syncthreads();
  write_lds(0, h0);
  write_lds(1, h1);
  __syncthreads();
  compute_chunk(0, 2);
  compute_chunk(1, 3);

  // fused epilogue: sc[b] = sum over this wave's 64 cols of nv*tanh(key + pqb)
  float sc[16];
#pragma unroll
  for (int i = 0; i < 16; ++i) sc[i] = 0.f;
#pragma unroll
  for (int n = 0; n < 4; ++n) {
    int col = w * 64 + n * 16 + lr;
    float nvc = nv[col];
#pragma unroll
    for (int m = 0; m < 4; ++m) {
#pragma unroll
      for (int r = 0; r < 4; ++r) {
        int brow = m * 16 + lk * 4 + r;
        float x = acc[m][n][r] + pqb[brow * EMB + col];
        sc[m * 4 + r] += nvc * fast_tanh(x);
      }
    }
  }
#pragma unroll
  for (int i = 0; i < 16; ++i) {
    float vsum = sc[i];
#pragma unroll
    for (int off = 1; off < 16; off <<= 1) vsum += __shfl_xor(vsum, off, 64);
    if (lr == 0) red[w][(i >> 2) * 16 + lk * 4 + (i & 3)] = vsum;
  }
  __syncthreads();
  if (t < BSZ) {
    float total = 0.f;
#pragma unroll
    for (int ww = 0; ww < 8; ++ww) total += red[ww][t];
    scoresT[(size_t)t * SRC + s] = total;
  }
}

// ---- softmax over s for each b; writes pT[b][s] and both attn outputs [s][b] ----
__global__ void softmax_k(const float* __restrict__ scoresT, const unsigned char* __restrict__ mask,
                          float* __restrict__ pT, float* __restrict__ attn0,
                          float* __restrict__ attn1) {
  __shared__ float buf[SRC];
  __shared__ float red[256];
  int b = blockIdx.x, t = threadIdx.x;
  float mx = -1e30f;
  for (int s = t; s < SRC; s += 256) {
    float x = scoresT[(size_t)b * SRC + s];
    if (mask[(size_t)s * BSZ + b]) x = -1e30f;
    buf[s] = x;
    mx = fmaxf(mx, x);
  }
  red[t] = mx; __syncthreads();
  for (int o = 128; o > 0; o >>= 1) { if (t < o) red[t] = fmaxf(red[t], red[t + o]); __syncthreads(); }
  mx = red[0]; __syncthreads();
  float sum = 0.f;
  for (int s = t; s < SRC; s += 256) { float e = __expf(buf[s] - mx); buf[s] = e; sum += e; }
  red[t] = sum; __syncthreads();
  for (int o = 128; o > 0; o >>= 1) { if (t < o) red[t] += red[t + o]; __syncthreads(); }
  float inv = 1.0f / red[0];
  for (int s = t; s < SRC; s += 256) {
    float p = buf[s] * inv;
    pT[(size_t)b * SRC + s] = p;
    attn0[(size_t)s * BSZ + b] = p;
    attn1[(size_t)s * BSZ + b] = p;
  }
}

// ---- context partials: parts[c][b][v] = sum_{s in chunk c(128)} p[s][b]*value[s][b][v] ----
// 2048 blocks (c*64+b), 128 threads, float4 per thread.
__global__ void ctx_partial(const float* __restrict__ value, const float* __restrict__ pT,
                            float* __restrict__ parts) {
  int blk = blockIdx.x;
  int c = blk >> 6;
  int b = blk & 63;
  int t = threadIdx.x;
  const float* pb = pT + (size_t)b * SRC + c * 128;
  float4 acc = make_float4(0.f, 0.f, 0.f, 0.f);
#pragma unroll 8
  for (int i = 0; i < 128; ++i) {
    float p = pb[i];
    float4 vv = *reinterpret_cast<const float4*>(
        value + ((size_t)((c * 128 + i) * BSZ + b)) * EMB + t * 4);
    acc.x += p * vv.x; acc.y += p * vv.y; acc.z += p * vv.z; acc.w += p * vv.w;
  }
  *reinterpret_cast<float4*>(parts + (size_t)blk * EMB + t * 4) = acc;
}

__global__ void ctx_reduce(const float* __restrict__ parts, float* __restrict__ out_ctx) {
  int idx = blockIdx.x * 256 + threadIdx.x;  // b*512 + v
  float acc = 0.f;
#pragma unroll
  for (int c = 0; c < 32; ++c) acc += parts[(size_t)c * (BSZ * EMB) + idx];
  out_ctx[idx] = acc;
}

extern "C" void kernel_launch(void* const* d_in, const int* in_sizes, int n_in,
                              void* d_out, int out_size, void* d_ws, size_t ws_size,
                              hipStream_t stream) {
  const float* query        = (const float*)d_in[0];
  const float* value        = (const float*)d_in[1];
  const unsigned char* mask = (const unsigned char*)d_in[2];
  const float* Wq           = (const float*)d_in[3];
  const float* Wv           = (const float*)d_in[4];
  const float* v            = (const float*)d_in[5];
  const float* bias         = (const float*)d_in[6];
  const float* g            = (const float*)d_in[7];

  float* out_ctx = (float*)d_out;              // [64][512]
  float* attn0   = (float*)d_out + BSZ * EMB;  // [4096][64]
  float* attn1   = attn0 + SRC * BSZ;

  char* ws = (char*)d_ws;
  float*  nv      = (float*)(ws);                              // 2 KB
  float*  pqb     = (float*)(ws + 2048);                       // 128 KB
  __bf16* wvpk    = (__bf16*)(ws + 2048 + 131072);             // 512 KB
  float*  scoresT = (float*)(ws + 2048 + 131072 + 524288);     // 1 MB [b][s]
  float*  pT      = scoresT + SRC * BSZ;                       // 1 MB [b][s]
  float*  parts   = pT + SRC * BSZ;                            // 4 MB [32][64][512]

  prep_nv<<<1, 256, 0, stream>>>(v, g, nv);
  prep_pqb<<<2 * BSZ, 256, 0, stream>>>(query, Wq, bias, pqb);
  pack_wv<<<128, 256, 0, stream>>>(Wv, wvpk);
  scores_kernel<<<SRC, 512, 0, stream>>>(value, pqb, nv, wvpk, scoresT);
  softmax_k<<<BSZ, 256, 0, stream>>>(scoresT, mask, pT, attn0, attn1);
  ctx_partial<<<BSZ * 32, 128, 0, stream>>>(value, pT, parts);
  ctx_reduce<<<128, 256, 0, stream>>>(parts, out_ctx);
}

// Round 3
// 962.122 us; speedup vs baseline: 1.0839x; 1.0704x over previous
//
#include <hip/hip_runtime.h>
#include <hip/hip_bf16.h>
#include <math.h>

typedef __bf16 bf16x8 __attribute__((ext_vector_type(8)));
typedef float  f32x4  __attribute__((ext_vector_type(4)));

#define SRC 4096
#define BSZ 64
#define EMB 512

// ---- fused prep: blk0 = normed_v; blk 1..128 = pack Wv; blk 129..256 = pqb ----
__global__ void prep_all(const float* __restrict__ query, const float* __restrict__ Wq,
                         const float* __restrict__ bias, const float* __restrict__ v,
                         const float* __restrict__ g, const float* __restrict__ Wv,
                         float* __restrict__ nv, float* __restrict__ pqb,
                         __bf16* __restrict__ wvpk) {
  __shared__ float sh[EMB];
  __shared__ float red[256];
  const int blk = blockIdx.x, t = threadIdx.x;
  if (blk == 0) {
    float a = v[t], b = v[t + 256];
    red[t] = a * a + b * b;
    __syncthreads();
    for (int o = 128; o > 0; o >>= 1) {
      if (t < o) red[t] += red[t + o];
      __syncthreads();
    }
    float scale = g[0] / sqrtf(red[0]);
    nv[t]       = a * scale;
    nv[t + 256] = b * scale;
  } else if (blk <= 128) {
    int tid  = (blk - 1) * 256 + t;   // 0..32767
    int lane = tid & 63;
    int ks   = (tid >> 6) & 15;
    int nsub = tid >> 10;
    int e  = nsub * 16 + (lane & 15);
    int k0 = ks * 32 + (lane >> 4) * 8;
    const float* src = Wv + (size_t)e * EMB + k0;
    bf16x8 o;
#pragma unroll
    for (int j = 0; j < 8; ++j) o[j] = (__bf16)src[j];
    *reinterpret_cast<bf16x8*>(wvpk + (size_t)tid * 8) = o;
  } else {
    int bb = blk - 129;               // 0..127
    int b = bb >> 1;
    int e = (bb & 1) * 256 + t;
    sh[t]       = query[b * EMB + t];
    sh[t + 256] = query[b * EMB + t + 256];
    __syncthreads();
    const float* wr = Wq + (size_t)e * EMB;
    float a0 = 0.f, a1 = 0.f;
#pragma unroll 8
    for (int k = 0; k < EMB; k += 8) {
      float4 q0 = *reinterpret_cast<const float4*>(&sh[k]);
      float4 w0 = *reinterpret_cast<const float4*>(&wr[k]);
      float4 q1 = *reinterpret_cast<const float4*>(&sh[k + 4]);
      float4 w1 = *reinterpret_cast<const float4*>(&wr[k + 4]);
      a0 += q0.x * w0.x + q0.y * w0.y + q0.z * w0.z + q0.w * w0.w;
      a1 += q1.x * w1.x + q1.y * w1.y + q1.z * w1.z + q1.w * w1.w;
    }
    pqb[b * EMB + e] = a0 + a1 + bias[e];
  }
}

// ---- fused scores: scoresT[b][s] = sum_e nv[e] * tanh(key[s][b][e] + pqb[b][e])
// One block per s. Phase 1: stage ALL of value[s] (64x512) as bf16 into LDS
// (xor-swizzled 16B granules, conflict-free). One barrier. Phase 2: pure MFMA
// compute with only L2-hot bq loads in the vmem queue (no HBM/vmcnt hazard).
__global__ __launch_bounds__(512, 4)
void scores_kernel(const float* __restrict__ value, const float* __restrict__ pqb,
                   const float* __restrict__ nv, const __bf16* __restrict__ wvpk,
                   float* __restrict__ scoresT) {
  __shared__ __bf16 As[BSZ * EMB];   // 64 KB; elem(row,kg*8+i) at row*512 + ((kg^(row&7))*8 + i)
  __shared__ float red[8][BSZ];
  const int s = blockIdx.x;
  const int t = threadIdx.x;

  // ---- stage ----
  {
    const int row = t >> 3, sub = t & 7;
    const float* src = value + (size_t)s * (BSZ * EMB) + (size_t)row * EMB + sub * 8;
#pragma unroll
    for (int j = 0; j < 8; ++j) {
      float4 v0 = *reinterpret_cast<const float4*>(src + j * 64);
      float4 v1 = *reinterpret_cast<const float4*>(src + j * 64 + 4);
      int kgp = (sub + j * 8) ^ (row & 7);
      bf16x8 o;
      o[0] = (__bf16)v0.x; o[1] = (__bf16)v0.y; o[2] = (__bf16)v0.z; o[3] = (__bf16)v0.w;
      o[4] = (__bf16)v1.x; o[5] = (__bf16)v1.y; o[6] = (__bf16)v1.z; o[7] = (__bf16)v1.w;
      *reinterpret_cast<bf16x8*>(&As[row * EMB + kgp * 8]) = o;
    }
  }
  __syncthreads();

  // ---- compute ----
  const int w = t >> 6, l = t & 63, lr = l & 15, lk = l >> 4;

  f32x4 acc[4][4];
#pragma unroll
  for (int m = 0; m < 4; ++m)
#pragma unroll
    for (int n = 0; n < 4; ++n)
#pragma unroll
      for (int r = 0; r < 4; ++r) acc[m][n][r] = 0.f;

  // bq slot for (nt, ksg) lives at wvpk + (nt*16 + ksg)*512 + l*8, nt = w*4+n
  const __bf16* bp = wvpk + (size_t)(w * 4) * 16 * 512 + (size_t)l * 8;
  bf16x8 bq[2][4];
#pragma unroll
  for (int n = 0; n < 4; ++n)
    bq[0][n] = *reinterpret_cast<const bf16x8*>(bp + (size_t)(n * 16) * 512);

#pragma unroll
  for (int ksg = 0; ksg < 16; ++ksg) {
    if (ksg < 15) {
#pragma unroll
      for (int n = 0; n < 4; ++n)
        bq[(ksg + 1) & 1][n] =
            *reinterpret_cast<const bf16x8*>(bp + (size_t)(n * 16 + ksg + 1) * 512);
    }
    const int kgp = ((ksg * 4 + lk) ^ (lr & 7)) * 8;
#pragma unroll
    for (int m = 0; m < 4; ++m) {
      bf16x8 a = *reinterpret_cast<const bf16x8*>(&As[(m * 16 + lr) * EMB + kgp]);
#pragma unroll
      for (int n = 0; n < 4; ++n)
        acc[m][n] = __builtin_amdgcn_mfma_f32_16x16x32_bf16(a, bq[ksg & 1][n], acc[m][n], 0, 0, 0);
    }
  }

  // ---- fused epilogue: sc[b] += nv[col]*tanh(acc + pqb) ----
  float sc[16];
#pragma unroll
  for (int i = 0; i < 16; ++i) sc[i] = 0.f;
#pragma unroll
  for (int n = 0; n < 4; ++n) {
    int col = w * 64 + n * 16 + lr;
    float nvc = nv[col];
#pragma unroll
    for (int m = 0; m < 4; ++m) {
#pragma unroll
      for (int r = 0; r < 4; ++r) {
        int brow = m * 16 + lk * 4 + r;
        float x = acc[m][n][r] + pqb[brow * EMB + col];
        // tanh(x) = 1 - 2/(1+exp(2x)) — monotone-safe at both infinities
        float e = __expf(2.0f * x);
        float rcp = __builtin_amdgcn_rcpf(1.0f + e);
        sc[m * 4 + r] += fmaf(-2.0f * nvc, rcp, nvc);
      }
    }
  }

#pragma unroll
  for (int i = 0; i < 16; ++i) {
    float vsum = sc[i];
#pragma unroll
    for (int off = 1; off < 16; off <<= 1) vsum += __shfl_xor(vsum, off, 64);
    if (lr == 0) red[w][(i >> 2) * 16 + lk * 4 + (i & 3)] = vsum;
  }
  __syncthreads();
  if (t < BSZ) {
    float total = 0.f;
#pragma unroll
    for (int ww = 0; ww < 8; ++ww) total += red[ww][t];
    scoresT[(size_t)t * SRC + s] = total;
  }
}

// ---- softmax over s for each b; writes pT[b][s] and both attn outputs [s][b] ----
__global__ void softmax_k(const float* __restrict__ scoresT, const unsigned char* __restrict__ mask,
                          float* __restrict__ pT, float* __restrict__ attn0,
                          float* __restrict__ attn1) {
  __shared__ float buf[SRC];
  __shared__ float red[256];
  int b = blockIdx.x, t = threadIdx.x;
  float mx = -1e30f;
  for (int s = t; s < SRC; s += 256) {
    float x = scoresT[(size_t)b * SRC + s];
    if (mask[(size_t)s * BSZ + b]) x = -1e30f;
    buf[s] = x;
    mx = fmaxf(mx, x);
  }
  red[t] = mx; __syncthreads();
  for (int o = 128; o > 0; o >>= 1) { if (t < o) red[t] = fmaxf(red[t], red[t + o]); __syncthreads(); }
  mx = red[0]; __syncthreads();
  float sum = 0.f;
  for (int s = t; s < SRC; s += 256) { float e = __expf(buf[s] - mx); buf[s] = e; sum += e; }
  red[t] = sum; __syncthreads();
  for (int o = 128; o > 0; o >>= 1) { if (t < o) red[t] += red[t + o]; __syncthreads(); }
  float inv = 1.0f / red[0];
  for (int s = t; s < SRC; s += 256) {
    float p = buf[s] * inv;
    pT[(size_t)b * SRC + s] = p;
    attn0[(size_t)s * BSZ + b] = p;
    attn1[(size_t)s * BSZ + b] = p;
  }
}

// ---- context partials: parts[cc][b][v] = sum_{s in half-chunk cc} p[s][b]*value[s][b][v]
// 1024 blocks (c*64+b), 256 threads: t = half(1b) x f4col(128). Wave-uniform p loads.
__global__ __launch_bounds__(256)
void ctx_partial(const float* __restrict__ value, const float* __restrict__ pT,
                 float* __restrict__ parts) {
  int blk = blockIdx.x;
  int c = blk >> 6;        // 0..15
  int b = blk & 63;
  int t = threadIdx.x;
  int f4 = t & 127, half = t >> 7;
  const float* pb = pT + (size_t)b * SRC + c * 256 + half;
  const float* vb = value + ((size_t)(c * 256 + half) * BSZ + b) * EMB + f4 * 4;
  float4 acc = make_float4(0.f, 0.f, 0.f, 0.f);
#pragma unroll 8
  for (int j = 0; j < 128; ++j) {
    float p = pb[j * 2];
    float4 vv = *reinterpret_cast<const float4*>(vb + (size_t)j * 2 * BSZ * EMB);
    acc.x += p * vv.x; acc.y += p * vv.y; acc.z += p * vv.z; acc.w += p * vv.w;
  }
  *reinterpret_cast<float4*>(parts + ((size_t)(c * 2 + half) * BSZ + b) * EMB + f4 * 4) = acc;
}

__global__ void ctx_reduce(const float* __restrict__ parts, float* __restrict__ out_ctx) {
  int idx = blockIdx.x * 256 + threadIdx.x;  // b*512 + v
  float acc = 0.f;
#pragma unroll
  for (int c = 0; c < 32; ++c) acc += parts[(size_t)c * (BSZ * EMB) + idx];
  out_ctx[idx] = acc;
}

extern "C" void kernel_launch(void* const* d_in, const int* in_sizes, int n_in,
                              void* d_out, int out_size, void* d_ws, size_t ws_size,
                              hipStream_t stream) {
  const float* query        = (const float*)d_in[0];
  const float* value        = (const float*)d_in[1];
  const unsigned char* mask = (const unsigned char*)d_in[2];
  const float* Wq           = (const float*)d_in[3];
  const float* Wv           = (const float*)d_in[4];
  const float* v            = (const float*)d_in[5];
  const float* bias         = (const float*)d_in[6];
  const float* g            = (const float*)d_in[7];

  float* out_ctx = (float*)d_out;              // [64][512]
  float* attn0   = (float*)d_out + BSZ * EMB;  // [4096][64]
  float* attn1   = attn0 + SRC * BSZ;

  char* ws = (char*)d_ws;
  float*  nv      = (float*)(ws);                              // 2 KB
  float*  pqb     = (float*)(ws + 2048);                       // 128 KB
  __bf16* wvpk    = (__bf16*)(ws + 2048 + 131072);             // 512 KB
  float*  scoresT = (float*)(ws + 2048 + 131072 + 524288);     // 1 MB [b][s]
  float*  pT      = scoresT + SRC * BSZ;                       // 1 MB [b][s]
  float*  parts   = pT + SRC * BSZ;                            // 4 MB [32][64][512]

  prep_all<<<257, 256, 0, stream>>>(query, Wq, bias, v, g, Wv, nv, pqb, wvpk);
  scores_kernel<<<SRC, 512, 0, stream>>>(value, pqb, nv, wvpk, scoresT);
  softmax_k<<<BSZ, 256, 0, stream>>>(scoresT, mask, pT, attn0, attn1);
  ctx_partial<<<BSZ * 16, 256, 0, stream>>>(value, pT, parts);
  ctx_reduce<<<128, 256, 0, stream>>>(parts, out_ctx);
}